// Round 1
// baseline (705.382 us; speedup 1.0000x reference)
//
#include <hip/hip_runtime.h>
#include <math.h>

#define LDIM 256
#define NCODES 1024
#define HID 256
#define NLAY 5
#define NVQ 4
#define CC_ 0.25f
#define OMEGA_ 30.0f
#define BATCH 16
#define NPTS 4096
#define PTILE 128   // points per siren block
#define KC 16       // K-chunk rows staged in LDS

// ---------------- Kernel A: residual VQ (one block per batch) ----------------
__global__ __launch_bounds__(256) void vq_kernel(const int* __restrict__ lidx,
                                                 const float* __restrict__ latents,
                                                 const float* __restrict__ emb,
                                                 float* __restrict__ ws) {
  __shared__ float Ech[32 * 260];   // 32 codes x 256 (stride 260 to break bank conflicts)
  __shared__ float r_s[LDIM];
  __shared__ float red[LDIM];
  __shared__ float mval[LDIM];
  __shared__ int   midx[LDIM];
  const int t = threadIdx.x;
  const int b = blockIdx.x;
  const int ib = lidx[b];

  float rd = 0.f;
  #pragma unroll
  for (int v = 0; v < NVQ; ++v) rd += latents[((size_t)ib * NVQ + v) * LDIM + t];
  r_s[t] = rd;
  float zq_sum = 0.f;
  float lossSum = 0.f;
  __syncthreads();

  const int cg = t >> 3;   // code-in-chunk 0..31
  const int dq = t & 7;    // d-part 0..7

  for (int s = 0; s < NVQ; ++s) {
    const float* E = emb + (size_t)s * NCODES * LDIM;
    const float4* E4 = (const float4*)E;
    float bestv = 3.4e38f; int besti = 0;
    for (int ch = 0; ch < 32; ++ch) {
      __syncthreads();
      #pragma unroll
      for (int it = 0; it < 8; ++it) {    // stage 32x256 floats, coalesced
        int f = it * 256 + t;
        int row = f >> 6;
        int col4 = f & 63;
        *(float4*)&Ech[row * 260 + col4 * 4] = E4[(size_t)(ch * 32 + row) * 64 + col4];
      }
      __syncthreads();
      float dot = 0.f, e2 = 0.f;
      const float* er = &Ech[cg * 260];
      const float4* rr4 = (const float4*)r_s;
      #pragma unroll
      for (int j = 0; j < 8; ++j) {
        int d4 = dq + 8 * j;              // interleaved to spread banks
        float4 e = *(const float4*)&er[d4 * 4];
        float4 r = rr4[d4];
        dot += e.x * r.x + e.y * r.y + e.z * r.z + e.w * r.w;
        e2  += e.x * e.x + e.y * e.y + e.z * e.z + e.w * e.w;
      }
      dot += __shfl_xor(dot, 1); e2 += __shfl_xor(e2, 1);
      dot += __shfl_xor(dot, 2); e2 += __shfl_xor(e2, 2);
      dot += __shfl_xor(dot, 4); e2 += __shfl_xor(e2, 4);
      if (dq == 0) {
        float dist = e2 - 2.f * dot;      // +||r||^2 constant: argmin-invariant
        int c = ch * 32 + cg;
        if (dist < bestv) { bestv = dist; besti = c; }
      }
    }
    mval[t] = (dq == 0) ? bestv : 3.4e38f;
    midx[t] = (dq == 0) ? besti : (1 << 30);
    __syncthreads();
    for (int off = 128; off > 0; off >>= 1) {
      if (t < off) {
        float ov = mval[t + off]; int oi = midx[t + off];
        if (ov < mval[t] || (ov == mval[t] && oi < midx[t])) { mval[t] = ov; midx[t] = oi; }
      }
      __syncthreads();
    }
    int cbest = midx[0];
    float zq = E[(size_t)cbest * LDIM + t];
    float diff = zq - rd;
    red[t] = diff * diff;
    __syncthreads();
    for (int off = 128; off > 0; off >>= 1) {
      if (t < off) red[t] += red[t + off];
      __syncthreads();
    }
    lossSum += red[0];
    zq_sum += zq;
    rd -= zq;
    r_s[t] = rd;
    __syncthreads();
  }
  ws[b * LDIM + t] = zq_sum;                 // effective_z
  if (t == 0) ws[4096 + b] = lossSum;        // raw sum_{s,d} diff^2
}

// ---------------- Kernel B: FiLM params (layers 1..4) + loss finalize ----------------
__global__ __launch_bounds__(256) void film_kernel(const float* __restrict__ mod_W,
                                                   const float* __restrict__ mod_b,
                                                   float* __restrict__ ws,
                                                   float* __restrict__ loss_out) {
  __shared__ float z_s[LDIM];
  const int t = threadIdx.x;
  const int li = blockIdx.x & 3;   // 0..3 -> layer 1..4
  const int b  = blockIdx.x >> 2;
  const int l  = li + 1;
  z_s[t] = ws[b * LDIM + t];
  __syncthreads();
  float m1 = mod_b[l * 2 * HID + t];
  float m2 = mod_b[l * 2 * HID + HID + t];
  const float* Wm = mod_W + (size_t)l * LDIM * 2 * HID;
  #pragma unroll 4
  for (int d = 0; d < LDIM; ++d) {
    float zd = z_s[d];
    m1 = fmaf(zd, Wm[d * 2 * HID + t], m1);
    m2 = fmaf(zd, Wm[d * 2 * HID + HID + t], m2);
  }
  float* film = ws + 8192;
  film[((b * 4 + li) * 2 + 0) * HID + t] = 1.f + m1;  // 1+gamma
  film[((b * 4 + li) * 2 + 1) * HID + t] = m2;        // beta
  if (blockIdx.x == 0 && t == 0) {
    float s = 0.f;
    for (int i = 0; i < BATCH; ++i) s += ws[4096 + i];
    loss_out[0] = s * (CC_ / (NVQ * BATCH * LDIM));
  }
}

// ---------------- Kernel C: fused SIREN decoder ----------------
__global__ __launch_bounds__(256, 1) void siren_kernel(
    const float* __restrict__ coords,
    const float* __restrict__ W0,
    const float* __restrict__ b0,
    const float* __restrict__ Wh,
    const float* __restrict__ bh,
    const float* __restrict__ Wl,
    const float* __restrict__ bl,
    const float* __restrict__ ws,
    float* __restrict__ out) {
  __shared__ float x_t[HID * PTILE];   // [d][p], 128 KB
  __shared__ float w_s[KC * HID];      // [k][h], 16 KB
  const int tid = threadIdx.x;
  const int bp = blockIdx.x;
  const int b = bp >> 5;               // 32 blocks per batch
  const int tile = bp & 31;
  const int pbase = b * NPTS + tile * PTILE;

  // ---- layer 0: x = sin(30*(coords@W0 + b0)) ----
  {
    const int p = tid & (PTILE - 1);
    const int d0 = (tid >> 7) * (HID / 2);
    const float c0 = coords[(size_t)(pbase + p) * 2 + 0];
    const float c1 = coords[(size_t)(pbase + p) * 2 + 1];
    for (int dj = 0; dj < HID / 2; ++dj) {
      int d = d0 + dj;
      float pre = fmaf(c0, W0[d], fmaf(c1, W0[HID + d], b0[d]));
      x_t[d * PTILE + p] = __sinf(OMEGA_ * pre);
    }
  }

  const int g  = tid & 15;
  const int hg = tid >> 4;
  const int p0a = 4 * g;
  const int p0b = 64 + 4 * g;
  const int h0 = hg * 16;

  float acc[8][16];
  const float* film = ws + 8192;

  for (int layer = 1; layer < NLAY; ++layer) {
    #pragma unroll
    for (int pi = 0; pi < 8; ++pi)
      #pragma unroll
      for (int hj = 0; hj < 16; ++hj) acc[pi][hj] = 0.f;

    const float* Wg = Wh + (size_t)(layer - 1) * HID * HID;
    for (int kc = 0; kc < HID; kc += KC) {
      __syncthreads();   // protects x_t writes (prev layer) and w_s reads (prev chunk)
      #pragma unroll
      for (int it = 0; it < 4; ++it) {   // stage KCx256 floats, coalesced
        int f = it * 256 + tid;
        int row = f >> 6;
        int col = (f & 63) * 4;
        *(float4*)&w_s[row * HID + col] = *(const float4*)&Wg[(size_t)(kc + row) * HID + col];
      }
      __syncthreads();
      #pragma unroll 2
      for (int kk = 0; kk < KC; ++kk) {
        const float* xr = &x_t[(kc + kk) * PTILE];
        float4 A0 = *(const float4*)(xr + p0a);
        float4 A1 = *(const float4*)(xr + p0b);
        const float* wr = &w_s[kk * HID + h0];
        float4 B0 = *(const float4*)(wr + 0);
        float4 B1 = *(const float4*)(wr + 4);
        float4 B2 = *(const float4*)(wr + 8);
        float4 B3 = *(const float4*)(wr + 12);
        float A[8]  = {A0.x, A0.y, A0.z, A0.w, A1.x, A1.y, A1.z, A1.w};
        float Bv[16] = {B0.x, B0.y, B0.z, B0.w, B1.x, B1.y, B1.z, B1.w,
                        B2.x, B2.y, B2.z, B2.w, B3.x, B3.y, B3.z, B3.w};
        #pragma unroll
        for (int pi = 0; pi < 8; ++pi)
          #pragma unroll
          for (int hj = 0; hj < 16; ++hj)
            acc[pi][hj] = fmaf(A[pi], Bv[hj], acc[pi][hj]);
      }
    }
    __syncthreads();   // all reads of old x_t complete
    const int li = layer - 1;
    const float* bhp = bh + li * HID;
    const float* fg = &film[((b * 4 + li) * 2 + 0) * HID];
    const float* fb = &film[((b * 4 + li) * 2 + 1) * HID];
    #pragma unroll
    for (int hj = 0; hj < 16; ++hj) {
      int h = h0 + hj;
      float bias = bhp[h];
      float g1 = fg[h];
      float bt = fb[h];
      float vals[8];
      #pragma unroll
      for (int pi = 0; pi < 8; ++pi) {
        float pre = acc[pi][hj] + bias;
        pre = fmaf(pre, g1, bt);          // pre*(1+gamma) + beta
        vals[pi] = __sinf(OMEGA_ * pre);
      }
      float4 v0 = {vals[0], vals[1], vals[2], vals[3]};
      float4 v1 = {vals[4], vals[5], vals[6], vals[7]};
      *(float4*)&x_t[h * PTILE + p0a] = v0;
      *(float4*)&x_t[h * PTILE + p0b] = v1;
    }
    // next iteration's first __syncthreads() protects these writes
  }
  __syncthreads();

  // ---- output layer: values = x @ Wl + bl ----
  if (tid < PTILE) {
    const int p = tid;
    float v0 = bl[0], v1 = bl[1], v2 = bl[2];
    for (int d = 0; d < HID; ++d) {
      float xv = x_t[d * PTILE + p];
      v0 = fmaf(xv, Wl[d * 3 + 0], v0);
      v1 = fmaf(xv, Wl[d * 3 + 1], v1);
      v2 = fmaf(xv, Wl[d * 3 + 2], v2);
    }
    size_t o = (size_t)(pbase + p) * 3;
    out[o + 0] = v0; out[o + 1] = v1; out[o + 2] = v2;
  }
}

extern "C" void kernel_launch(void* const* d_in, const int* in_sizes, int n_in,
                              void* d_out, int out_size, void* d_ws, size_t ws_size,
                              hipStream_t stream) {
  (void)in_sizes; (void)n_in; (void)ws_size;
  const float* coords  = (const float*)d_in[0];
  const int*   lidx    = (const int*)d_in[1];
  const float* latents = (const float*)d_in[2];
  const float* emb     = (const float*)d_in[3];
  const float* mod_W   = (const float*)d_in[4];
  const float* mod_b   = (const float*)d_in[5];
  const float* W0      = (const float*)d_in[6];
  const float* b0      = (const float*)d_in[7];
  const float* Wh      = (const float*)d_in[8];
  const float* bh      = (const float*)d_in[9];
  const float* Wl      = (const float*)d_in[10];
  const float* bl      = (const float*)d_in[11];
  float* out = (float*)d_out;
  float* ws  = (float*)d_ws;
  float* loss_out = out + (out_size - 1);   // 16*4096*3 = 196608

  vq_kernel<<<BATCH, 256, 0, stream>>>(lidx, latents, emb, ws);
  film_kernel<<<BATCH * 4, 256, 0, stream>>>(mod_W, mod_b, ws, loss_out);
  siren_kernel<<<(BATCH * NPTS) / PTILE, 256, 0, stream>>>(coords, W0, b0, Wh, bh, Wl, bl, ws, out);
}

// Round 4
// 576.137 us; speedup vs baseline: 1.2243x; 1.2243x over previous
//
#include <hip/hip_runtime.h>
#include <math.h>

#define LDIM 256
#define NCODES 1024
#define HID 256
#define NLAY 5
#define NVQ 4
#define CC_ 0.25f
#define OMEGA_ 30.0f
#define BATCH 16
#define NPTS 4096
#define PTILE 128   // points per siren block
#define KC 16       // K-chunk rows staged in LDS

// ws layout (floats):
//   [0     .. 4095 ] residual r        (16 x 256)
//   [4096  .. 8191 ] zq_sum / effective_z (16 x 256)
//   [8192  .. 40959] FiLM params (written by film_kernel, read by siren)
//   -- before film_kernel runs, the head of the film region is VQ scratch:
//   [8192  .. 8207 ] per-batch loss accumulator (16)
//   [8208  .. 8335 ] scan partial best-dist (128)
//   [8336  .. 8463 ] scan partial best-idx  (128, int bitcast)
// Max footprint 40960 floats = 163,840 B (same as the round-1-proven layout).

// ---------------- VQ init: residual = sum_v latents, zero accumulators ----------------
__global__ __launch_bounds__(256) void vq_init(const int* __restrict__ lidx,
                                               const float* __restrict__ latents,
                                               float* __restrict__ ws) {
  const int t = threadIdx.x, b = blockIdx.x;
  const int ib = lidx[b];
  float z = 0.f;
  #pragma unroll
  for (int v = 0; v < NVQ; ++v) z += latents[((size_t)ib * NVQ + v) * LDIM + t];
  ws[b * LDIM + t] = z;            // residual
  ws[4096 + b * LDIM + t] = 0.f;   // zq_sum
  if (t == 0) ws[8192 + b] = 0.f;  // loss accumulator
}

// ---------------- VQ scan: partial argmin over a 128-code slice ----------------
__global__ __launch_bounds__(256) void vq_scan(const float* __restrict__ emb,
                                               float* __restrict__ ws, int stage) {
  __shared__ __align__(16) float Ech[32 * 260];  // 32 codes x 256 (stride 260: conflict-free)
  __shared__ __align__(16) float r_s[LDIM];
  __shared__ float mval[256];
  __shared__ int   midx[256];
  const int t = threadIdx.x;
  const int b = blockIdx.x >> 3;
  const int slice = blockIdx.x & 7;
  r_s[t] = ws[b * LDIM + t];
  __syncthreads();
  const float* E = emb + (size_t)stage * NCODES * LDIM + (size_t)slice * 128 * LDIM;
  const float4* E4 = (const float4*)E;
  const int cg = t >> 3;   // code-in-chunk 0..31
  const int dq = t & 7;    // d-part 0..7
  float bestv = 3.4e38f; int besti = 0;
  for (int ch = 0; ch < 4; ++ch) {
    __syncthreads();
    #pragma unroll
    for (int it = 0; it < 8; ++it) {    // stage 32x256 floats, coalesced
      int f = it * 256 + t;
      int row = f >> 6;
      int col4 = f & 63;
      *(float4*)&Ech[row * 260 + col4 * 4] = E4[(size_t)(ch * 32 + row) * 64 + col4];
    }
    __syncthreads();
    float dot = 0.f, e2 = 0.f;
    const float* er = &Ech[cg * 260];
    const float4* rr4 = (const float4*)r_s;
    #pragma unroll
    for (int j = 0; j < 8; ++j) {
      int d4 = dq + 8 * j;              // interleaved to spread banks
      float4 e = *(const float4*)&er[d4 * 4];
      float4 r = rr4[d4];
      dot += e.x * r.x + e.y * r.y + e.z * r.z + e.w * r.w;
      e2  += e.x * e.x + e.y * e.y + e.z * e.z + e.w * e.w;
    }
    dot += __shfl_xor(dot, 1); e2 += __shfl_xor(e2, 1);
    dot += __shfl_xor(dot, 2); e2 += __shfl_xor(e2, 2);
    dot += __shfl_xor(dot, 4); e2 += __shfl_xor(e2, 4);
    if (dq == 0) {
      float dist = e2 - 2.f * dot;      // +||r||^2 constant: argmin-invariant
      int c = slice * 128 + ch * 32 + cg;
      if (dist < bestv) { bestv = dist; besti = c; }
    }
  }
  mval[t] = (dq == 0) ? bestv : 3.4e38f;
  midx[t] = (dq == 0) ? besti : (1 << 30);
  __syncthreads();
  for (int off = 128; off > 0; off >>= 1) {
    if (t < off) {
      float ov = mval[t + off]; int oi = midx[t + off];
      if (ov < mval[t] || (ov == mval[t] && oi < midx[t])) { mval[t] = ov; midx[t] = oi; }
    }
    __syncthreads();
  }
  if (t == 0) {
    ws[8208 + b * 8 + slice] = mval[0];
    ((int*)ws)[8336 + b * 8 + slice] = midx[0];
  }
}

// ---------------- VQ update: combine partials, update residual/zq_sum/loss ----------------
__global__ __launch_bounds__(256) void vq_update(const float* __restrict__ emb,
                                                 float* __restrict__ ws, int stage) {
  __shared__ int bestIdx;
  __shared__ float red[256];
  const int t = threadIdx.x;
  const int b = blockIdx.x;
  if (t == 0) {
    float bv = ws[8208 + b * 8];
    int bi = ((const int*)ws)[8336 + b * 8];
    for (int s2 = 1; s2 < 8; ++s2) {
      float v = ws[8208 + b * 8 + s2];
      int i2 = ((const int*)ws)[8336 + b * 8 + s2];
      if (v < bv || (v == bv && i2 < bi)) { bv = v; bi = i2; }  // first-index tie-break
    }
    bestIdx = bi;
  }
  __syncthreads();
  const float* E = emb + (size_t)stage * NCODES * LDIM;
  float r = ws[b * LDIM + t];
  float zq = E[(size_t)bestIdx * LDIM + t];
  float diff = zq - r;
  red[t] = diff * diff;
  __syncthreads();
  for (int off = 128; off > 0; off >>= 1) {
    if (t < off) red[t] += red[t + off];
    __syncthreads();
  }
  if (t == 0) ws[8192 + b] += red[0];
  ws[4096 + b * LDIM + t] += zq;   // zq_sum
  ws[b * LDIM + t] = r - zq;       // residual
}

// ---------------- FiLM params (layers 1..4) + loss finalize ----------------
__global__ __launch_bounds__(256) void film_kernel(const float* __restrict__ mod_W,
                                                   const float* __restrict__ mod_b,
                                                   float* __restrict__ ws,
                                                   float* __restrict__ loss_out) {
  __shared__ float z_s[LDIM];
  const int t = threadIdx.x;
  // read loss BEFORE block 0 overwrites the scratch head of the film region
  if (blockIdx.x == 0 && t == 0) {
    float s = 0.f;
    for (int i = 0; i < BATCH; ++i) s += ws[8192 + i];
    loss_out[0] = s * (CC_ / (NVQ * BATCH * LDIM));
  }
  __syncthreads();
  const int li = blockIdx.x & 3;   // 0..3 -> layer 1..4
  const int b  = blockIdx.x >> 2;
  const int l  = li + 1;
  z_s[t] = ws[4096 + b * LDIM + t];
  __syncthreads();
  float m1 = mod_b[l * 2 * HID + t];
  float m2 = mod_b[l * 2 * HID + HID + t];
  const float* Wm = mod_W + (size_t)l * LDIM * 2 * HID;
  #pragma unroll 4
  for (int d = 0; d < LDIM; ++d) {
    float zd = z_s[d];
    m1 = fmaf(zd, Wm[d * 2 * HID + t], m1);
    m2 = fmaf(zd, Wm[d * 2 * HID + HID + t], m2);
  }
  float* film = ws + 8192;
  film[((b * 4 + li) * 2 + 0) * HID + t] = 1.f + m1;  // 1+gamma
  film[((b * 4 + li) * 2 + 1) * HID + t] = m2;        // beta
}

// ---------------- Fused SIREN decoder (512 thr = 2 waves/SIMD) ----------------
__global__ __launch_bounds__(512, 1) void siren_kernel(
    const float* __restrict__ coords,
    const float* __restrict__ W0,
    const float* __restrict__ b0,
    const float* __restrict__ Wh,
    const float* __restrict__ bh,
    const float* __restrict__ Wl,
    const float* __restrict__ bl,
    const float* __restrict__ ws,
    float* __restrict__ out) {
  __shared__ __align__(16) float x_t[HID * PTILE];   // [d][p], 128 KB
  __shared__ __align__(16) float w_s[KC * HID];      // [k][h], 16 KB
  const int tid = threadIdx.x;
  const int bp = blockIdx.x;
  const int b = bp >> 5;               // 32 blocks per batch
  const int tile = bp & 31;
  const int pbase = b * NPTS + tile * PTILE;

  // ---- layer 0: x = sin(30*(coords@W0 + b0)) ----
  {
    const int p = tid & (PTILE - 1);
    const int d0 = (tid >> 7) * (HID / 4);   // 4 quarters of 64 dims
    const float c0 = coords[(size_t)(pbase + p) * 2 + 0];
    const float c1 = coords[(size_t)(pbase + p) * 2 + 1];
    for (int dj = 0; dj < HID / 4; ++dj) {
      int d = d0 + dj;
      float pre = fmaf(c0, W0[d], fmaf(c1, W0[HID + d], b0[d]));
      x_t[d * PTILE + p] = __sinf(OMEGA_ * pre);
    }
  }

  const int pg = tid & 15;     // 16 p-groups x 8p = 128 p
  const int hg = tid >> 4;     // 32 h-groups x 8h = 256 h
  const int p0 = pg * 8;
  const int h0 = hg * 8;

  float acc[8][8];
  const float* film = ws + 8192;

  for (int layer = 1; layer < NLAY; ++layer) {
    #pragma unroll
    for (int pi = 0; pi < 8; ++pi)
      #pragma unroll
      for (int hj = 0; hj < 8; ++hj) acc[pi][hj] = 0.f;

    const float* Wg = Wh + (size_t)(layer - 1) * HID * HID;
    for (int kc = 0; kc < HID; kc += KC) {
      __syncthreads();   // protects x_t writes (prev layer) and w_s reads (prev chunk)
      #pragma unroll
      for (int it = 0; it < 2; ++it) {   // stage KCx256 floats, coalesced
        int f = it * 512 + tid;
        int row = f >> 6;
        int col = (f & 63) * 4;
        *(float4*)&w_s[row * HID + col] = *(const float4*)&Wg[(size_t)(kc + row) * HID + col];
      }
      __syncthreads();
      #pragma unroll 4
      for (int kk = 0; kk < KC; ++kk) {
        const float* xr = &x_t[(kc + kk) * PTILE];
        float4 A0 = *(const float4*)(xr + p0);
        float4 A1 = *(const float4*)(xr + p0 + 4);
        const float* wr = &w_s[kk * HID + h0];
        float4 B0 = *(const float4*)(wr + 0);
        float4 B1 = *(const float4*)(wr + 4);
        float A[8]  = {A0.x, A0.y, A0.z, A0.w, A1.x, A1.y, A1.z, A1.w};
        float Bv[8] = {B0.x, B0.y, B0.z, B0.w, B1.x, B1.y, B1.z, B1.w};
        #pragma unroll
        for (int pi = 0; pi < 8; ++pi)
          #pragma unroll
          for (int hj = 0; hj < 8; ++hj)
            acc[pi][hj] = fmaf(A[pi], Bv[hj], acc[pi][hj]);
      }
    }
    __syncthreads();   // all reads of old x_t complete
    const int li = layer - 1;
    const float* bhp = bh + li * HID;
    const float* fg = &film[((b * 4 + li) * 2 + 0) * HID];
    const float* fb = &film[((b * 4 + li) * 2 + 1) * HID];
    #pragma unroll
    for (int hj = 0; hj < 8; ++hj) {
      int h = h0 + hj;
      float bias = bhp[h];
      float g1 = fg[h];
      float bt = fb[h];
      float vals[8];
      #pragma unroll
      for (int pi = 0; pi < 8; ++pi) {
        float pre = acc[pi][hj] + bias;
        pre = fmaf(pre, g1, bt);          // pre*(1+gamma) + beta
        vals[pi] = __sinf(OMEGA_ * pre);
      }
      float4 v0 = {vals[0], vals[1], vals[2], vals[3]};
      float4 v1 = {vals[4], vals[5], vals[6], vals[7]};
      *(float4*)&x_t[h * PTILE + p0] = v0;
      *(float4*)&x_t[h * PTILE + p0 + 4] = v1;
    }
    // next iteration's first __syncthreads() protects these writes
  }
  __syncthreads();

  // ---- output layer: values = x @ Wl + bl ----
  if (tid < PTILE) {
    const int p = tid;
    float v0 = bl[0], v1 = bl[1], v2 = bl[2];
    for (int d = 0; d < HID; ++d) {
      float xv = x_t[d * PTILE + p];
      v0 = fmaf(xv, Wl[d * 3 + 0], v0);
      v1 = fmaf(xv, Wl[d * 3 + 1], v1);
      v2 = fmaf(xv, Wl[d * 3 + 2], v2);
    }
    size_t o = (size_t)(pbase + p) * 3;
    out[o + 0] = v0; out[o + 1] = v1; out[o + 2] = v2;
  }
}

extern "C" void kernel_launch(void* const* d_in, const int* in_sizes, int n_in,
                              void* d_out, int out_size, void* d_ws, size_t ws_size,
                              hipStream_t stream) {
  (void)in_sizes; (void)n_in; (void)ws_size;
  const float* coords  = (const float*)d_in[0];
  const int*   lidx    = (const int*)d_in[1];
  const float* latents = (const float*)d_in[2];
  const float* emb     = (const float*)d_in[3];
  const float* mod_W   = (const float*)d_in[4];
  const float* mod_b   = (const float*)d_in[5];
  const float* W0      = (const float*)d_in[6];
  const float* b0      = (const float*)d_in[7];
  const float* Wh      = (const float*)d_in[8];
  const float* bh      = (const float*)d_in[9];
  const float* Wl      = (const float*)d_in[10];
  const float* bl      = (const float*)d_in[11];
  float* out = (float*)d_out;
  float* ws  = (float*)d_ws;
  float* loss_out = out + (out_size - 1);   // 16*4096*3 = 196608

  vq_init<<<BATCH, 256, 0, stream>>>(lidx, latents, ws);
  for (int s = 0; s < NVQ; ++s) {
    vq_scan<<<BATCH * 8, 256, 0, stream>>>(emb, ws, s);
    vq_update<<<BATCH, 256, 0, stream>>>(emb, ws, s);
  }
  film_kernel<<<BATCH * 4, 256, 0, stream>>>(mod_W, mod_b, ws, loss_out);
  siren_kernel<<<(BATCH * NPTS) / PTILE, 512, 0, stream>>>(coords, W0, b0, Wh, bh, Wl, bl, ws, out);
}

// Round 5
// 557.485 us; speedup vs baseline: 1.2653x; 1.0335x over previous
//
#include <hip/hip_runtime.h>
#include <math.h>

#define LDIM 256
#define NCODES 1024
#define HID 256
#define NLAY 5
#define NVQ 4
#define CC_ 0.25f
#define OMEGA_ 30.0f
#define BATCH 16
#define NPTS 4096
#define PTILE 128   // points per siren block
#define KC 16       // K-chunk rows staged in LDS

// ws layout (floats):
//   [0     .. 4095 ] residual r        (16 x 256)
//   [4096  .. 8191 ] zq_sum / effective_z (16 x 256)
//   [8192  .. 40959] FiLM params (written by film_kernel, read by siren)
//   -- before film_kernel runs, the head of the film region is VQ scratch:
//   [8192  .. 8207 ] per-batch loss accumulator (16)
//   [8208  .. 8335 ] scan partial best-dist (128)
//   [8336  .. 8463 ] scan partial best-idx  (128, int bitcast)

// ---------------- VQ init ----------------
__global__ __launch_bounds__(256) void vq_init(const int* __restrict__ lidx,
                                               const float* __restrict__ latents,
                                               float* __restrict__ ws) {
  const int t = threadIdx.x, b = blockIdx.x;
  const int ib = lidx[b];
  float z = 0.f;
  #pragma unroll
  for (int v = 0; v < NVQ; ++v) z += latents[((size_t)ib * NVQ + v) * LDIM + t];
  ws[b * LDIM + t] = z;            // residual
  ws[4096 + b * LDIM + t] = 0.f;   // zq_sum
  if (t == 0) ws[8192 + b] = 0.f;  // loss accumulator
}

// ---------------- VQ scan: partial argmin over a 128-code slice ----------------
__global__ __launch_bounds__(256) void vq_scan(const float* __restrict__ emb,
                                               float* __restrict__ ws, int stage) {
  __shared__ __align__(16) float Ech[32 * 260];  // 32 codes x 256 (stride 260: conflict-free)
  __shared__ __align__(16) float r_s[LDIM];
  __shared__ float mval[256];
  __shared__ int   midx[256];
  const int t = threadIdx.x;
  const int b = blockIdx.x >> 3;
  const int slice = blockIdx.x & 7;
  r_s[t] = ws[b * LDIM + t];
  __syncthreads();
  const float* E = emb + (size_t)stage * NCODES * LDIM + (size_t)slice * 128 * LDIM;
  const float4* E4 = (const float4*)E;
  const int cg = t >> 3;   // code-in-chunk 0..31
  const int dq = t & 7;    // d-part 0..7
  float bestv = 3.4e38f; int besti = 0;
  for (int ch = 0; ch < 4; ++ch) {
    __syncthreads();
    #pragma unroll
    for (int it = 0; it < 8; ++it) {    // stage 32x256 floats, coalesced
      int f = it * 256 + t;
      int row = f >> 6;
      int col4 = f & 63;
      *(float4*)&Ech[row * 260 + col4 * 4] = E4[(size_t)(ch * 32 + row) * 64 + col4];
    }
    __syncthreads();
    float dot = 0.f, e2 = 0.f;
    const float* er = &Ech[cg * 260];
    const float4* rr4 = (const float4*)r_s;
    #pragma unroll
    for (int j = 0; j < 8; ++j) {
      int d4 = dq + 8 * j;              // interleaved to spread banks
      float4 e = *(const float4*)&er[d4 * 4];
      float4 r = rr4[d4];
      dot += e.x * r.x + e.y * r.y + e.z * r.z + e.w * r.w;
      e2  += e.x * e.x + e.y * e.y + e.z * e.z + e.w * e.w;
    }
    dot += __shfl_xor(dot, 1); e2 += __shfl_xor(e2, 1);
    dot += __shfl_xor(dot, 2); e2 += __shfl_xor(e2, 2);
    dot += __shfl_xor(dot, 4); e2 += __shfl_xor(e2, 4);
    if (dq == 0) {
      float dist = e2 - 2.f * dot;      // +||r||^2 constant: argmin-invariant
      int c = slice * 128 + ch * 32 + cg;
      if (dist < bestv) { bestv = dist; besti = c; }
    }
  }
  mval[t] = (dq == 0) ? bestv : 3.4e38f;
  midx[t] = (dq == 0) ? besti : (1 << 30);
  __syncthreads();
  for (int off = 128; off > 0; off >>= 1) {
    if (t < off) {
      float ov = mval[t + off]; int oi = midx[t + off];
      if (ov < mval[t] || (ov == mval[t] && oi < midx[t])) { mval[t] = ov; midx[t] = oi; }
    }
    __syncthreads();
  }
  if (t == 0) {
    ws[8208 + b * 8 + slice] = mval[0];
    ((int*)ws)[8336 + b * 8 + slice] = midx[0];
  }
}

// ---------------- VQ update: combine partials, update residual/zq_sum/loss ----------------
__global__ __launch_bounds__(256) void vq_update(const float* __restrict__ emb,
                                                 float* __restrict__ ws, int stage) {
  __shared__ int bestIdx;
  __shared__ float red[256];
  const int t = threadIdx.x;
  const int b = blockIdx.x;
  if (t == 0) {
    float bv = ws[8208 + b * 8];
    int bi = ((const int*)ws)[8336 + b * 8];
    for (int s2 = 1; s2 < 8; ++s2) {
      float v = ws[8208 + b * 8 + s2];
      int i2 = ((const int*)ws)[8336 + b * 8 + s2];
      if (v < bv || (v == bv && i2 < bi)) { bv = v; bi = i2; }  // first-index tie-break
    }
    bestIdx = bi;
  }
  __syncthreads();
  const float* E = emb + (size_t)stage * NCODES * LDIM;
  float r = ws[b * LDIM + t];
  float zq = E[(size_t)bestIdx * LDIM + t];
  float diff = zq - r;
  red[t] = diff * diff;
  __syncthreads();
  for (int off = 128; off > 0; off >>= 1) {
    if (t < off) red[t] += red[t + off];
    __syncthreads();
  }
  if (t == 0) ws[8192 + b] += red[0];
  ws[4096 + b * LDIM + t] += zq;   // zq_sum
  ws[b * LDIM + t] = r - zq;       // residual
}

// ---------------- FiLM params (layers 1..4) + loss finalize ----------------
__global__ __launch_bounds__(256) void film_kernel(const float* __restrict__ mod_W,
                                                   const float* __restrict__ mod_b,
                                                   float* __restrict__ ws,
                                                   float* __restrict__ loss_out) {
  __shared__ float z_s[LDIM];
  const int t = threadIdx.x;
  // read loss BEFORE block 0 overwrites the scratch head of the film region
  if (blockIdx.x == 0 && t == 0) {
    float s = 0.f;
    for (int i = 0; i < BATCH; ++i) s += ws[8192 + i];
    loss_out[0] = s * (CC_ / (NVQ * BATCH * LDIM));
  }
  __syncthreads();
  const int li = blockIdx.x & 3;   // 0..3 -> layer 1..4
  const int b  = blockIdx.x >> 2;
  const int l  = li + 1;
  z_s[t] = ws[4096 + b * LDIM + t];
  __syncthreads();
  float m1 = mod_b[l * 2 * HID + t];
  float m2 = mod_b[l * 2 * HID + HID + t];
  const float* Wm = mod_W + (size_t)l * LDIM * 2 * HID;
  #pragma unroll 4
  for (int d = 0; d < LDIM; ++d) {
    float zd = z_s[d];
    m1 = fmaf(zd, Wm[d * 2 * HID + t], m1);
    m2 = fmaf(zd, Wm[d * 2 * HID + HID + t], m2);
  }
  float* film = ws + 8192;
  film[((b * 4 + li) * 2 + 0) * HID + t] = 1.f + m1;  // 1+gamma
  film[((b * 4 + li) * 2 + 1) * HID + t] = m2;        // beta
}

// ---------------- Fused SIREN decoder (512 thr, conflict-free LDS geometry) ----------------
__global__ __launch_bounds__(512, 1) void siren_kernel(
    const float* __restrict__ coords,
    const float* __restrict__ W0,
    const float* __restrict__ b0,
    const float* __restrict__ Wh,
    const float* __restrict__ bh,
    const float* __restrict__ Wl,
    const float* __restrict__ bl,
    const float* __restrict__ ws,
    float* __restrict__ out) {
  __shared__ __align__(16) float x_t[HID * PTILE];   // [d][p], 128 KB
  __shared__ __align__(16) float w_s[KC * HID];      // [k][h], 16 KB
  const int tid = threadIdx.x;
  const int bp = blockIdx.x;
  const int b = bp >> 5;               // 32 blocks per batch
  const int tile = bp & 31;
  const int pbase = b * NPTS + tile * PTILE;

  // ---- layer 0: x = sin(30*(coords@W0 + b0)) ----
  {
    const int p = tid & (PTILE - 1);
    const int d0 = (tid >> 7) * (HID / 4);   // 4 quarters of 64 dims
    const float c0 = coords[(size_t)(pbase + p) * 2 + 0];
    const float c1 = coords[(size_t)(pbase + p) * 2 + 1];
    for (int dj = 0; dj < HID / 4; ++dj) {
      int d = d0 + dj;
      float pre = fmaf(c0, W0[d], fmaf(c1, W0[HID + d], b0[d]));
      x_t[d * PTILE + p] = __sinf(OMEGA_ * pre);
    }
  }

  // bank-conflict-free mapping (round-1-proven):
  //   A: two float4 at p0a=4g, p0b=64+4g -> 8 lanes span all 32 banks, rest broadcast
  //   B: float4 at h0=hg*8 -> 4 distinct addrs/wave, broadcast (free)
  const int g  = tid & 15;
  const int hg = tid >> 4;     // 0..31
  const int p0a = 4 * g;
  const int p0b = 64 + 4 * g;
  const int h0 = hg * 8;

  float acc[8][8];             // [p 0..7 = {p0a+0..3, p0b+0..3}][h 0..7]
  const float* film = ws + 8192;

  for (int layer = 1; layer < NLAY; ++layer) {
    #pragma unroll
    for (int pi = 0; pi < 8; ++pi)
      #pragma unroll
      for (int hj = 0; hj < 8; ++hj) acc[pi][hj] = 0.f;

    const float* Wg = Wh + (size_t)(layer - 1) * HID * HID;
    for (int kc = 0; kc < HID; kc += KC) {
      __syncthreads();   // protects x_t writes (prev layer) and w_s reads (prev chunk)
      #pragma unroll
      for (int it = 0; it < 2; ++it) {   // stage KCx256 floats, coalesced
        int f = it * 512 + tid;
        int row = f >> 6;
        int col = (f & 63) * 4;
        *(float4*)&w_s[row * HID + col] = *(const float4*)&Wg[(size_t)(kc + row) * HID + col];
      }
      __syncthreads();
      #pragma unroll 4
      for (int kk = 0; kk < KC; ++kk) {
        const float* xr = &x_t[(kc + kk) * PTILE];
        float4 A0 = *(const float4*)(xr + p0a);
        float4 A1 = *(const float4*)(xr + p0b);
        const float* wr = &w_s[kk * HID + h0];
        float4 B0 = *(const float4*)(wr + 0);
        float4 B1 = *(const float4*)(wr + 4);
        float A[8]  = {A0.x, A0.y, A0.z, A0.w, A1.x, A1.y, A1.z, A1.w};
        float Bv[8] = {B0.x, B0.y, B0.z, B0.w, B1.x, B1.y, B1.z, B1.w};
        #pragma unroll
        for (int pi = 0; pi < 8; ++pi)
          #pragma unroll
          for (int hj = 0; hj < 8; ++hj)
            acc[pi][hj] = fmaf(A[pi], Bv[hj], acc[pi][hj]);
      }
    }
    __syncthreads();   // all reads of old x_t complete
    const int li = layer - 1;
    const float* bhp = bh + li * HID;
    const float* fg = &film[((b * 4 + li) * 2 + 0) * HID];
    const float* fb = &film[((b * 4 + li) * 2 + 1) * HID];
    #pragma unroll
    for (int hj = 0; hj < 8; ++hj) {
      int h = h0 + hj;
      float bias = bhp[h];
      float g1 = fg[h];
      float bt = fb[h];
      float vals[8];
      #pragma unroll
      for (int pi = 0; pi < 8; ++pi) {
        float pre = acc[pi][hj] + bias;
        pre = fmaf(pre, g1, bt);          // pre*(1+gamma) + beta
        vals[pi] = __sinf(OMEGA_ * pre);
      }
      float4 v0 = {vals[0], vals[1], vals[2], vals[3]};
      float4 v1 = {vals[4], vals[5], vals[6], vals[7]};
      *(float4*)&x_t[h * PTILE + p0a] = v0;   // banks 4g: conflict-free per 8-lane phase
      *(float4*)&x_t[h * PTILE + p0b] = v1;
    }
    // next iteration's first __syncthreads() protects these writes
  }
  __syncthreads();

  // ---- output layer: values = x @ Wl + bl ----
  if (tid < PTILE) {
    const int p = tid;
    float v0 = bl[0], v1 = bl[1], v2 = bl[2];
    for (int d = 0; d < HID; ++d) {
      float xv = x_t[d * PTILE + p];
      v0 = fmaf(xv, Wl[d * 3 + 0], v0);
      v1 = fmaf(xv, Wl[d * 3 + 1], v1);
      v2 = fmaf(xv, Wl[d * 3 + 2], v2);
    }
    size_t o = (size_t)(pbase + p) * 3;
    out[o + 0] = v0; out[o + 1] = v1; out[o + 2] = v2;
  }
}

extern "C" void kernel_launch(void* const* d_in, const int* in_sizes, int n_in,
                              void* d_out, int out_size, void* d_ws, size_t ws_size,
                              hipStream_t stream) {
  (void)in_sizes; (void)n_in; (void)ws_size;
  const float* coords  = (const float*)d_in[0];
  const int*   lidx    = (const int*)d_in[1];
  const float* latents = (const float*)d_in[2];
  const float* emb     = (const float*)d_in[3];
  const float* mod_W   = (const float*)d_in[4];
  const float* mod_b   = (const float*)d_in[5];
  const float* W0      = (const float*)d_in[6];
  const float* b0      = (const float*)d_in[7];
  const float* Wh      = (const float*)d_in[8];
  const float* bh      = (const float*)d_in[9];
  const float* Wl      = (const float*)d_in[10];
  const float* bl      = (const float*)d_in[11];
  float* out = (float*)d_out;
  float* ws  = (float*)d_ws;
  float* loss_out = out + (out_size - 1);   // 16*4096*3 = 196608

  vq_init<<<BATCH, 256, 0, stream>>>(lidx, latents, ws);
  for (int s = 0; s < NVQ; ++s) {
    vq_scan<<<BATCH * 8, 256, 0, stream>>>(emb, ws, s);
    vq_update<<<BATCH, 256, 0, stream>>>(emb, ws, s);
  }
  film_kernel<<<BATCH * 4, 256, 0, stream>>>(mod_W, mod_b, ws, loss_out);
  siren_kernel<<<(BATCH * NPTS) / PTILE, 512, 0, stream>>>(coords, W0, b0, Wh, bh, Wl, bl, ws, out);
}

// Round 8
// 272.537 us; speedup vs baseline: 2.5882x; 2.0455x over previous
//
#include <hip/hip_runtime.h>
#include <math.h>

#define LDIM 256
#define NCODES 1024
#define HID 256
#define NLAY 5
#define NVQ 4
#define CC_ 0.25f
#define OMEGA_ 30.0f
#define BATCH 16
#define NPTS 4096
#define PTILE 128

// ws layout (floats) — max footprint 40960 floats = 163,840 B (round-1-proven):
//   [0..4095]      residual  [4096..8191] zq_sum/effective_z
//   [8192..40959]  FiLM params (film_kernel) / VQ scratch head before that

typedef __attribute__((ext_vector_type(8))) short short8;
typedef __attribute__((ext_vector_type(4))) float f32x4;

// truncation hi/lo split: x ~= hi + lo, |err| <~ 2^-17 |x|
__device__ __forceinline__ unsigned int pack_split(float x) {
  unsigned int u = __builtin_bit_cast(unsigned int, x);
  float hf = __builtin_bit_cast(float, u & 0xffff0000u);
  float lf = x - hf;
  unsigned int ul = __builtin_bit_cast(unsigned int, lf);
  return (u & 0xffff0000u) | (ul >> 16);
}
__device__ __forceinline__ void split_trunc(float x, short& hi, short& lo) {
  unsigned int u = __builtin_bit_cast(unsigned int, x);
  float hf = __builtin_bit_cast(float, u & 0xffff0000u);
  float lf = x - hf;
  hi = (short)(u >> 16);
  lo = (short)(__builtin_bit_cast(unsigned int, lf) >> 16);
}
__device__ __forceinline__ float bf16_hi_f(unsigned short h) {
  return __builtin_bit_cast(float, (unsigned int)h << 16);
}

// ---------------- VQ init ----------------
__global__ __launch_bounds__(256) void vq_init(const int* __restrict__ lidx,
                                               const float* __restrict__ latents,
                                               float* __restrict__ ws) {
  const int t = threadIdx.x, b = blockIdx.x;
  const int ib = lidx[b];
  float z = 0.f;
  #pragma unroll
  for (int v = 0; v < NVQ; ++v) z += latents[((size_t)ib * NVQ + v) * LDIM + t];
  ws[b * LDIM + t] = z;
  ws[4096 + b * LDIM + t] = 0.f;
  if (t == 0) ws[8192 + b] = 0.f;
}

// ---------------- VQ scan: partial argmin over a 128-code slice ----------------
__global__ __launch_bounds__(256) void vq_scan(const float* __restrict__ emb,
                                               float* __restrict__ ws, int stage) {
  __shared__ __align__(16) float Ech[32 * 260];
  __shared__ __align__(16) float r_s[LDIM];
  __shared__ float mval[256];
  __shared__ int   midx[256];
  const int t = threadIdx.x;
  const int b = blockIdx.x >> 3;
  const int slice = blockIdx.x & 7;
  r_s[t] = ws[b * LDIM + t];
  __syncthreads();
  const float* E = emb + (size_t)stage * NCODES * LDIM + (size_t)slice * 128 * LDIM;
  const float4* E4 = (const float4*)E;
  const int cg = t >> 3;
  const int dq = t & 7;
  float bestv = 3.4e38f; int besti = 0;
  for (int ch = 0; ch < 4; ++ch) {
    __syncthreads();
    #pragma unroll
    for (int it = 0; it < 8; ++it) {
      int f = it * 256 + t;
      int row = f >> 6;
      int col4 = f & 63;
      *(float4*)&Ech[row * 260 + col4 * 4] = E4[(size_t)(ch * 32 + row) * 64 + col4];
    }
    __syncthreads();
    float dot = 0.f, e2 = 0.f;
    const float* er = &Ech[cg * 260];
    const float4* rr4 = (const float4*)r_s;
    #pragma unroll
    for (int j = 0; j < 8; ++j) {
      int d4 = dq + 8 * j;
      float4 e = *(const float4*)&er[d4 * 4];
      float4 r = rr4[d4];
      dot += e.x * r.x + e.y * r.y + e.z * r.z + e.w * r.w;
      e2  += e.x * e.x + e.y * e.y + e.z * e.z + e.w * e.w;
    }
    dot += __shfl_xor(dot, 1); e2 += __shfl_xor(e2, 1);
    dot += __shfl_xor(dot, 2); e2 += __shfl_xor(e2, 2);
    dot += __shfl_xor(dot, 4); e2 += __shfl_xor(e2, 4);
    if (dq == 0) {
      float dist = e2 - 2.f * dot;
      int c = slice * 128 + ch * 32 + cg;
      if (dist < bestv) { bestv = dist; besti = c; }
    }
  }
  mval[t] = (dq == 0) ? bestv : 3.4e38f;
  midx[t] = (dq == 0) ? besti : (1 << 30);
  __syncthreads();
  for (int off = 128; off > 0; off >>= 1) {
    if (t < off) {
      float ov = mval[t + off]; int oi = midx[t + off];
      if (ov < mval[t] || (ov == mval[t] && oi < midx[t])) { mval[t] = ov; midx[t] = oi; }
    }
    __syncthreads();
  }
  if (t == 0) {
    ws[8208 + b * 8 + slice] = mval[0];
    ((int*)ws)[8336 + b * 8 + slice] = midx[0];
  }
}

// ---------------- VQ update ----------------
__global__ __launch_bounds__(256) void vq_update(const float* __restrict__ emb,
                                                 float* __restrict__ ws, int stage) {
  __shared__ int bestIdx;
  __shared__ float red[256];
  const int t = threadIdx.x;
  const int b = blockIdx.x;
  if (t == 0) {
    float bv = ws[8208 + b * 8];
    int bi = ((const int*)ws)[8336 + b * 8];
    for (int s2 = 1; s2 < 8; ++s2) {
      float v = ws[8208 + b * 8 + s2];
      int i2 = ((const int*)ws)[8336 + b * 8 + s2];
      if (v < bv || (v == bv && i2 < bi)) { bv = v; bi = i2; }
    }
    bestIdx = bi;
  }
  __syncthreads();
  const float* E = emb + (size_t)stage * NCODES * LDIM;
  float r = ws[b * LDIM + t];
  float zq = E[(size_t)bestIdx * LDIM + t];
  float diff = zq - r;
  red[t] = diff * diff;
  __syncthreads();
  for (int off = 128; off > 0; off >>= 1) {
    if (t < off) red[t] += red[t + off];
    __syncthreads();
  }
  if (t == 0) ws[8192 + b] += red[0];
  ws[4096 + b * LDIM + t] += zq;
  ws[b * LDIM + t] = r - zq;
}

// ---------------- FiLM params + loss finalize ----------------
__global__ __launch_bounds__(256) void film_kernel(const float* __restrict__ mod_W,
                                                   const float* __restrict__ mod_b,
                                                   float* __restrict__ ws,
                                                   float* __restrict__ loss_out) {
  __shared__ float z_s[LDIM];
  const int t = threadIdx.x;
  if (blockIdx.x == 0 && t == 0) {
    float s = 0.f;
    for (int i = 0; i < BATCH; ++i) s += ws[8192 + i];
    loss_out[0] = s * (CC_ / (NVQ * BATCH * LDIM));
  }
  __syncthreads();
  const int li = blockIdx.x & 3;
  const int b  = blockIdx.x >> 2;
  const int l  = li + 1;
  z_s[t] = ws[4096 + b * LDIM + t];
  __syncthreads();
  float m1 = mod_b[l * 2 * HID + t];
  float m2 = mod_b[l * 2 * HID + HID + t];
  const float* Wm = mod_W + (size_t)l * LDIM * 2 * HID;
  #pragma unroll 4
  for (int d = 0; d < LDIM; ++d) {
    float zd = z_s[d];
    m1 = fmaf(zd, Wm[d * 2 * HID + t], m1);
    m2 = fmaf(zd, Wm[d * 2 * HID + HID + t], m2);
  }
  float* film = ws + 8192;
  film[((b * 4 + li) * 2 + 0) * HID + t] = 1.f + m1;
  film[((b * 4 + li) * 2 + 1) * HID + t] = m2;
}

// ---------------- Fused SIREN decoder: split-bf16 MFMA, B direct from L2 ----------------
// x in LDS packed (hi<<16|lo) uint32, [128 p][260] (2-way banks max).
// Wave tile 64p x 64h = 4x4 MFMA tiles (16x16x32 bf16), 3-term split product.
__global__ __launch_bounds__(512) void siren_mfma(
    const float* __restrict__ coords,
    const float* __restrict__ W0,
    const float* __restrict__ b0,
    const float* __restrict__ Whg,
    const float* __restrict__ bhv,
    const float* __restrict__ Wl,
    const float* __restrict__ bl,
    const float* __restrict__ ws,
    float* __restrict__ out) {
  __shared__ unsigned int x_u[128 * 260];   // 133,120 B
  __shared__ float osum[128 * 4 * 3];       // 6,144 B
  const int tid = threadIdx.x;
  const int bp = blockIdx.x;
  const int b = bp >> 5;
  const int tile = bp & 31;
  const int pbase = b * NPTS + tile * PTILE;

  // ---- layer 0: fp32 VALU, split-pack into x_u ----
  {
    const int quarter = tid >> 7;          // 0..3 -> 64-d chunk
    const int p = tid & 127;
    const float c0 = coords[(size_t)(pbase + p) * 2 + 0];
    const float c1 = coords[(size_t)(pbase + p) * 2 + 1];
    const int d0 = quarter * 64;
    for (int i = 0; i < 64; i += 4) {
      unsigned int buf[4];
      #pragma unroll
      for (int j = 0; j < 4; ++j) {
        int d = d0 + i + j;
        float pre = fmaf(c0, W0[d], fmaf(c1, W0[HID + d], b0[d]));
        buf[j] = pack_split(__sinf(OMEGA_ * pre));
      }
      *(uint4*)&x_u[p * 260 + d0 + i] = *(uint4*)buf;
    }
  }

  const int lane = tid & 63;
  const int wv = tid >> 6;        // wave 0..7
  const int pg = wv & 1;          // 2 p-groups of 64
  const int hq = wv >> 1;         // 4 h-quarters of 64
  const int pb = pg * 64;
  const int hb = hq * 64;
  const int n = lane & 15;        // MFMA free-dim lane index
  const int q = lane >> 4;        // quad

  const float* film = ws + 8192;

  for (int layer = 1; layer < NLAY; ++layer) {
    const int li = layer - 1;
    f32x4 acc[4][4];
    #pragma unroll
    for (int pt = 0; pt < 4; ++pt)
      #pragma unroll
      for (int ht = 0; ht < 4; ++ht)
        acc[pt][ht] = (f32x4){0.f, 0.f, 0.f, 0.f};

    __syncthreads();   // x_u complete (layer-0 writes or previous epilogue)

    for (int kc = 0; kc < HID; kc += 32) {
      // B-frags direct from Whg (L2): lane n -> h = hb+ht*16+n, k = kc+q*8+j
      // (h contiguous across 16 lanes -> coalesced 64B segments; k strided)
      short8 Bh[4], Bl[4];
      #pragma unroll
      for (int ht = 0; ht < 4; ++ht) {
        const float* wbase = Whg + ((size_t)(li * 256 + kc + q * 8)) * 256 + hb + ht * 16 + n;
        #pragma unroll
        for (int j = 0; j < 8; ++j) {
          short hi, lo;
          split_trunc(wbase[(size_t)j * 256], hi, lo);
          Bh[ht][j] = hi; Bl[ht][j] = lo;
        }
      }
      // A-frags from LDS: m = lane&15 -> p = pb+pt*16+n, k = kc+q*8+j
      short8 ah[4], al[4];
      #pragma unroll
      for (int pt = 0; pt < 4; ++pt) {
        const uint4* ap = (const uint4*)&x_u[(pb + pt * 16 + n) * 260 + kc + q * 8];
        uint4 a0 = ap[0], a1 = ap[1];
        unsigned int aw[8] = {a0.x, a0.y, a0.z, a0.w, a1.x, a1.y, a1.z, a1.w};
        #pragma unroll
        for (int j = 0; j < 8; ++j) {
          ah[pt][j] = (short)(aw[j] >> 16);
          al[pt][j] = (short)(aw[j] & 0xffffu);
        }
      }
      #pragma unroll
      for (int ht = 0; ht < 4; ++ht) {
        #pragma unroll
        for (int pt = 0; pt < 4; ++pt) {
          acc[pt][ht] = __builtin_amdgcn_mfma_f32_16x16x32_bf16(ah[pt], Bh[ht], acc[pt][ht], 0, 0, 0);
          acc[pt][ht] = __builtin_amdgcn_mfma_f32_16x16x32_bf16(ah[pt], Bl[ht], acc[pt][ht], 0, 0, 0);
          acc[pt][ht] = __builtin_amdgcn_mfma_f32_16x16x32_bf16(al[pt], Bh[ht], acc[pt][ht], 0, 0, 0);
        }
      }
    }

    __syncthreads();   // all K-loop reads of x_u done before overwrite

    // epilogue: bias + FiLM + sin, split-pack back into x_u
    // D layout: col(h)=lane&15, row(p)=q*4+r  [m89-verified]
    #pragma unroll
    for (int ht = 0; ht < 4; ++ht) {
      const int h = hb + ht * 16 + n;
      const float bias = bhv[li * HID + h];
      const float g1 = film[((b * 4 + li) * 2 + 0) * HID + h];
      const float bt = film[((b * 4 + li) * 2 + 1) * HID + h];
      #pragma unroll
      for (int pt = 0; pt < 4; ++pt) {
        #pragma unroll
        for (int r = 0; r < 4; ++r) {
          float pre = acc[pt][ht][r] + bias;
          pre = fmaf(pre, g1, bt);
          x_u[(pb + pt * 16 + q * 4 + r) * 260 + h] = pack_split(__sinf(OMEGA_ * pre));
        }
      }
    }
    // next iteration's top __syncthreads protects these writes
  }
  __syncthreads();

  // ---- output layer: values = x @ Wl + bl (fp32 VALU, partials in osum) ----
  {
    const int p = tid >> 2;
    const int dq = tid & 3;
    float v0 = 0.f, v1 = 0.f, v2 = 0.f;
    for (int i = 0; i < 64; ++i) {
      int d = dq * 64 + i;
      unsigned int wrd = x_u[p * 260 + d];
      float xv = bf16_hi_f((unsigned short)(wrd >> 16)) +
                 bf16_hi_f((unsigned short)(wrd & 0xffffu));
      v0 = fmaf(xv, Wl[d * 3 + 0], v0);
      v1 = fmaf(xv, Wl[d * 3 + 1], v1);
      v2 = fmaf(xv, Wl[d * 3 + 2], v2);
    }
    osum[(p * 4 + dq) * 3 + 0] = v0;
    osum[(p * 4 + dq) * 3 + 1] = v1;
    osum[(p * 4 + dq) * 3 + 2] = v2;
  }
  __syncthreads();
  if (tid < PTILE) {
    const int p = tid;
    float v[3] = {bl[0], bl[1], bl[2]};
    #pragma unroll
    for (int dq = 0; dq < 4; ++dq)
      #pragma unroll
      for (int c = 0; c < 3; ++c) v[c] += osum[(p * 4 + dq) * 3 + c];
    size_t o = (size_t)(pbase + p) * 3;
    out[o + 0] = v[0]; out[o + 1] = v[1]; out[o + 2] = v[2];
  }
}

extern "C" void kernel_launch(void* const* d_in, const int* in_sizes, int n_in,
                              void* d_out, int out_size, void* d_ws, size_t ws_size,
                              hipStream_t stream) {
  (void)in_sizes; (void)n_in; (void)ws_size;
  const float* coords  = (const float*)d_in[0];
  const int*   lidx    = (const int*)d_in[1];
  const float* latents = (const float*)d_in[2];
  const float* emb     = (const float*)d_in[3];
  const float* mod_W   = (const float*)d_in[4];
  const float* mod_b   = (const float*)d_in[5];
  const float* W0      = (const float*)d_in[6];
  const float* b0      = (const float*)d_in[7];
  const float* Wh      = (const float*)d_in[8];
  const float* bh      = (const float*)d_in[9];
  const float* Wl      = (const float*)d_in[10];
  const float* bl      = (const float*)d_in[11];
  float* out = (float*)d_out;
  float* ws  = (float*)d_ws;
  float* loss_out = out + (out_size - 1);

  vq_init<<<BATCH, 256, 0, stream>>>(lidx, latents, ws);
  for (int s = 0; s < NVQ; ++s) {
    vq_scan<<<BATCH * 8, 256, 0, stream>>>(emb, ws, s);
    vq_update<<<BATCH, 256, 0, stream>>>(emb, ws, s);
  }
  film_kernel<<<BATCH * 4, 256, 0, stream>>>(mod_W, mod_b, ws, loss_out);
  siren_mfma<<<(BATCH * NPTS) / PTILE, 512, 0, stream>>>(coords, W0, b0, Wh, bh, Wl, bl, ws, out);
}